// Round 4
// baseline (287.271 us; speedup 1.0000x reference)
//
#include <hip/hip_runtime.h>
#include <math.h>
#include <stdint.h>

#define NLEV 16
#define TSIZE (1u << 19)
#define NB 4096
#define NS 48
#define NPTS (NB * NS)

typedef __attribute__((ext_vector_type(8))) short short8;
typedef __attribute__((ext_vector_type(4))) float f32x4;

struct Scales { float s[NLEV]; };

__device__ __forceinline__ uint32_t hash3(uint32_t x, uint32_t y, uint32_t z) {
    return (x ^ (y * 2654435761u) ^ (z * 805459861u)) & (TSIZE - 1u);
}

__device__ __forceinline__ float sigmoidf(float v) {
    return 1.0f / (1.0f + expf(-v));
}

// fp32 -> bf16 (round to nearest even), raw ushort bits
__device__ __forceinline__ ushort f2b(float f) {
    union { float f; uint32_t u; } v; v.f = f;
    uint32_t r = (v.u + 0x7FFFu + ((v.u >> 16) & 1u)) >> 16;
    return (ushort)r;
}

// relu + pack 2 fp32 -> 1 u32 of 2 bf16 (lo = first arg). Bit-math RNE.
__device__ __forceinline__ uint32_t pk_relu2(float a, float b) {
    a = fmaxf(a, 0.0f);
    b = fmaxf(b, 0.0f);
    return ((uint32_t)f2b(b) << 16) | (uint32_t)f2b(a);
}

__device__ __forceinline__ uint2 pack4_relu(f32x4 c, f32x4 bias) {
    uint2 o;
    o.x = pk_relu2(c[0] + bias[0], c[1] + bias[1]);
    o.y = pk_relu2(c[2] + bias[2], c[3] + bias[3]);
    return o;
}

// Compiler fence + LDS drain: per-wave write->read chaining (the earlier race
// was COMPILER reordering; HW DS is in-order per wave).
#define LDS_FENCE() asm volatile("s_waitcnt lgkmcnt(0)" ::: "memory")

#define MFMA16(a, b, c) __builtin_amdgcn_mfma_f32_16x16x32_bf16((a), (b), (c), 0, 0, 0)

// kA: one-block weight-bank build (20 frags x 512 ushort = 20 KB).
//   f0..3 W1^T | f4..5 W2^T | f6..9 H1^T | f10..17 H2^T (nt*2+kk) |
//   f18..19 H3^T (cols>=3 zero); frag element [lane][j] = W[k=quad*8+j][out=f*16+l15]
__global__ __launch_bounds__(256) void bank_kernel(
    const float* __restrict__ w1, const float* __restrict__ w2,
    const float* __restrict__ h1, const float* __restrict__ h2,
    const float* __restrict__ h3, ushort* __restrict__ bank)
{
    for (int idx = threadIdx.x; idx < 20 * 512; idx += 256) {
        const int f    = idx >> 9;
        const int r    = idx & 511;
        const int lane = r >> 3;
        const int j    = r & 7;
        const int l15  = lane & 15;
        const int quad = lane >> 4;
        const int k8   = quad * 8 + j;
        float val;
        if (f < 4) {
            val = w1[k8 * 64 + f * 16 + l15];
        } else if (f < 6) {
            val = w2[((f - 4) * 32 + k8) * 16 + l15];
        } else if (f < 10) {
            val = h1[k8 * 64 + (f - 6) * 16 + l15];
        } else if (f < 18) {
            const int t = f - 10, nt = t >> 1, kk = t & 1;
            val = h2[(kk * 32 + k8) * 64 + nt * 16 + l15];
        } else {
            val = (l15 < 3) ? h3[((f - 18) * 32 + k8) * 3 + l15] : 0.0f;
        }
        bank[idx] = f2b(val);
    }
}

// kB: FUSED encode + MLP + softmax-reduce. One 64-thread wave per batch.
// Key idea: the L1 MFMA B-fragment element [n=pt=l15][k=quad*8+j] is the
// (feat j&1) of level quad*4+(j>>1) for point 16t+l15 — i.e. each lane's
// fragment = 12 (pt,level) encode results. So each lane ENCODES its own 12
// pairs directly into registers: no enc_ws round-trip (-25 MB traffic,
// -6M requests), no second launch, and the request-bound gather phase
// overlaps the MFMA/VALU tail phase across the ~16 resident blocks/CU.
// Encode arithmetic per (pt,level) is bit-identical to the round-3 kernel.
__global__ __launch_bounds__(64) void fused_kernel(
    const float* __restrict__ positions,
    const float* __restrict__ densities,
    const float* __restrict__ normals,
    const float* __restrict__ c2w,
    const float* __restrict__ table,
    const ushort* __restrict__ bank,
    const float* __restrict__ b1, const float* __restrict__ b2,
    const float* __restrict__ hb1, const float* __restrict__ hb2,
    const float* __restrict__ hb3,
    float* __restrict__ out,
    Scales sc)
{
    __shared__ ushort bufA[48 * 72];
    __shared__ ushort bufB[48 * 72];
    __shared__ ushort bufC[48 * 40];

    const int bidb = blockIdx.x;       // batch
    const int p0   = bidb * NS;
    const int lane = threadIdx.x;
    const int l15  = lane & 15;
    const int quad = lane >> 4;

    // ---- per-lane scales for its 4 levels (quad*4+jj); sc.s[const] are
    // uniform SGPR reads, selected by quad via 3 cndmask per jj ----
    float sq[4];
#pragma unroll
    for (int jj = 0; jj < 4; ++jj) {
        float v = sc.s[jj];
        v = (quad == 1) ? sc.s[4 + jj]  : v;
        v = (quad == 2) ? sc.s[8 + jj]  : v;
        v = (quad == 3) ? sc.s[12 + jj] : v;
        sq[jj] = v;
    }

    // ---- camera transform for this lane's 3 points (pt = 16t + l15) ----
    const float* M = c2w + bidb * 12;  // wave-uniform
    float qx[3], qy[3], qz[3];
#pragma unroll
    for (int t = 0; t < 3; ++t) {
        const int p = p0 + 16 * t + l15;
        const float px = positions[3 * p + 0];
        const float py = positions[3 * p + 1];
        const float pz = positions[3 * p + 2];
        const float dx = px - M[3], dy = py - M[7], dz = pz - M[11];
        float x = M[0] * dx + M[4] * dy + M[8] * dz;
        float y = M[1] * dx + M[5] * dy + M[9] * dz;
        float z = M[2] * dx + M[6] * dy + M[10] * dz;
        x = (x + 1.0f) * 0.5f;
        y = (y + 1.0f) * 0.5f;
        z = (z + 1.0f) * 0.5f;
        const bool sel = (x > 0.0f) && (x < 1.0f) &&
                         (y > 0.0f) && (y < 1.0f) &&
                         (z > 0.0f) && (z < 1.0f);
        qx[t] = sel ? x : 0.0f;
        qy[t] = sel ? y : 0.0f;
        qz[t] = sel ? z : 0.0f;
    }

    // ---- encode 12 (pt,level) pairs straight into X fragments ----
    union XU { uint32_t u[4]; short8 s; };
    XU xu[3];
#pragma unroll
    for (int t = 0; t < 3; ++t) {
#pragma unroll
        for (int jj = 0; jj < 4; ++jj) {
            const float s  = sq[jj];
            const float sx = qx[t] * s, sy = qy[t] * s, sz = qz[t] * s;
            const float fx = floorf(sx), fy = floorf(sy), fz = floorf(sz);
            const float cx = ceilf(sx),  cy = ceilf(sy),  cz = ceilf(sz);
            const float ox = sx - fx, oy = sy - fy, oz = sz - fz;
            const uint32_t fxi = (uint32_t)fx, fyi = (uint32_t)fy, fzi = (uint32_t)fz;
            const uint32_t cxi = (uint32_t)cx, cyi = (uint32_t)cy, czi = (uint32_t)cz;

            const float2* tab = (const float2*)table + (uint32_t)(quad * 4 + jj) * TSIZE;
            const float2 g0 = tab[hash3(cxi, cyi, czi)];
            const float2 g1 = tab[hash3(cxi, fyi, czi)];
            const float2 g2 = tab[hash3(fxi, fyi, czi)];
            const float2 g3 = tab[hash3(fxi, cyi, czi)];
            const float2 g4 = tab[hash3(cxi, cyi, fzi)];
            const float2 g5 = tab[hash3(cxi, fyi, fzi)];
            const float2 g6 = tab[hash3(fxi, fyi, fzi)];
            const float2 g7 = tab[hash3(fxi, cyi, fzi)];

            const float omx = 1.0f - ox, omy = 1.0f - oy, omz = 1.0f - oz;
            float f03x = g0.x * ox + g3.x * omx, f03y = g0.y * ox + g3.y * omx;
            float f12x = g1.x * ox + g2.x * omx, f12y = g1.y * ox + g2.y * omx;
            float f56x = g5.x * ox + g6.x * omx, f56y = g5.y * ox + g6.y * omx;
            float f47x = g4.x * ox + g7.x * omx, f47y = g4.y * ox + g7.y * omx;
            float ax = f03x * oy + f12x * omy, ay = f03y * oy + f12y * omy;
            float bx = f47x * oy + f56x * omy, by = f47y * oy + f56y * omy;
            const float ex = ax * oz + bx * omz;
            const float ey = ay * oz + by * omz;
            xu[t].u[jj] = ((uint32_t)f2b(ey) << 16) | (uint32_t)f2b(ex);
        }
    }

    // ---- SH16 (identical for the whole batch): lane keeps sh[l15],
    // scattered to bufC rows (12 cheap b16 writes). ----
    {
        const float n0 = normals[3 * bidb + 0];
        const float n1 = normals[3 * bidb + 1];
        const float n2 = normals[3 * bidb + 2];
        float x = M[0] * n0 + M[4] * n1 + M[8] * n2;
        float y = M[1] * n0 + M[5] * n1 + M[9] * n2;
        float z = M[2] * n0 + M[6] * n1 + M[10] * n2;
        x = (x + 1.0f) * 0.5f;
        y = (y + 1.0f) * 0.5f;
        z = (z + 1.0f) * 0.5f;
        const float xx = x * x, yy = y * y, zz = z * z;
        float v = 0.28209479177387814f;
        v = (l15 == 1)  ? -0.48860251190291987f * y : v;
        v = (l15 == 2)  ?  0.48860251190291987f * z : v;
        v = (l15 == 3)  ? -0.48860251190291987f * x : v;
        v = (l15 == 4)  ?  1.0925484305920792f * x * y : v;
        v = (l15 == 5)  ? -1.0925484305920792f * y * z : v;
        v = (l15 == 6)  ?  0.94617469575756f * zz - 0.31539156525252f : v;
        v = (l15 == 7)  ? -1.0925484305920792f * x * z : v;
        v = (l15 == 8)  ?  0.5462742152960396f * (xx - yy) : v;
        v = (l15 == 9)  ?  0.5900435899266435f * y * (3.0f * xx - yy) : v;
        v = (l15 == 10) ?  2.890611442640554f * x * y * z : v;
        v = (l15 == 11) ?  0.4570457994644657f * y * (5.0f * zz - 1.0f) : v;
        v = (l15 == 12) ?  0.37317633259011546f * z * (5.0f * zz - 3.0f) : v;
        v = (l15 == 13) ?  0.4570457994644657f * x * (5.0f * zz - 1.0f) : v;
        v = (l15 == 14) ?  1.445305721320277f * z * (xx - yy) : v;
        v = (l15 == 15) ?  0.5900435899266435f * x * (xx - 3.0f * yy) : v;
        const ushort shb = f2b(v);
#pragma unroll
        for (int i = 0; i < 12; ++i)
            bufC[(i * 4 + quad) * 40 + l15] = shb;
    }

    const ushort* fb = bank + lane * 8;
#define FRAG(f) (*(const short8*)(fb + (f) * 512))

    const f32x4 zero = {0.0f, 0.0f, 0.0f, 0.0f};

    // ---- L1: W1^T(A) x X(B regs) -> 64, +b1, relu -> bufB [point][feat] ----
    {
        short8 w[4];
#pragma unroll
        for (int nt = 0; nt < 4; ++nt) w[nt] = FRAG(nt);
        f32x4 c[3][4];
        __builtin_amdgcn_s_setprio(1);
#pragma unroll
        for (int t = 0; t < 3; ++t)
#pragma unroll
            for (int nt = 0; nt < 4; ++nt) c[t][nt] = MFMA16(w[nt], xu[t].s, zero);
        __builtin_amdgcn_s_setprio(0);
        f32x4 b1q[4];
#pragma unroll
        for (int nt = 0; nt < 4; ++nt) b1q[nt] = *(const f32x4*)&b1[nt * 16 + quad * 4];
#pragma unroll
        for (int t = 0; t < 3; ++t)
#pragma unroll
            for (int nt = 0; nt < 4; ++nt)
                *(uint2*)&bufB[(16 * t + l15) * 72 + nt * 16 + quad * 4] =
                    pack4_relu(c[t][nt], b1q[nt]);
    }
    LDS_FENCE();

    // ---- L2: W2^T(A) x A1(B) -> 16 geo, +b2, relu -> bufC cols 16..31 ----
    {
        const short8 w0 = FRAG(4), w1f = FRAG(5);
        const f32x4 b2q = *(const f32x4*)&b2[quad * 4];
        f32x4 c[3];
        __builtin_amdgcn_s_setprio(1);
#pragma unroll
        for (int t = 0; t < 3; ++t) {
            const short8 a0 = *(const short8*)&bufB[(16 * t + l15) * 72 + quad * 8];
            const short8 a1 = *(const short8*)&bufB[(16 * t + l15) * 72 + 32 + quad * 8];
            c[t] = MFMA16(w0, a0, zero);
            c[t] = MFMA16(w1f, a1, c[t]);
        }
        __builtin_amdgcn_s_setprio(0);
#pragma unroll
        for (int t = 0; t < 3; ++t)
            *(uint2*)&bufC[(16 * t + l15) * 40 + 16 + quad * 4] = pack4_relu(c[t], b2q);
    }
    LDS_FENCE();

    // ---- L3: H1^T(A) x HIN(B) -> 64, +hb1, relu -> bufA ----
    {
        short8 w[4];
#pragma unroll
        for (int nt = 0; nt < 4; ++nt) w[nt] = FRAG(6 + nt);
        f32x4 c[3][4];
        __builtin_amdgcn_s_setprio(1);
#pragma unroll
        for (int t = 0; t < 3; ++t) {
            const short8 a = *(const short8*)&bufC[(16 * t + l15) * 40 + quad * 8];
#pragma unroll
            for (int nt = 0; nt < 4; ++nt) c[t][nt] = MFMA16(w[nt], a, zero);
        }
        __builtin_amdgcn_s_setprio(0);
        f32x4 hb1q[4];
#pragma unroll
        for (int nt = 0; nt < 4; ++nt) hb1q[nt] = *(const f32x4*)&hb1[nt * 16 + quad * 4];
#pragma unroll
        for (int t = 0; t < 3; ++t)
#pragma unroll
            for (int nt = 0; nt < 4; ++nt)
                *(uint2*)&bufA[(16 * t + l15) * 72 + nt * 16 + quad * 4] =
                    pack4_relu(c[t][nt], hb1q[nt]);
    }
    LDS_FENCE();

    // ---- L4: H2^T(A) x U(B) -> 64, +hb2, relu -> bufB (V) ----
    {
        short8 w[8];
#pragma unroll
        for (int f = 0; f < 8; ++f) w[f] = FRAG(10 + f);
        f32x4 c[3][4];
        __builtin_amdgcn_s_setprio(1);
#pragma unroll
        for (int t = 0; t < 3; ++t) {
            const short8 a0 = *(const short8*)&bufA[(16 * t + l15) * 72 + quad * 8];
            const short8 a1 = *(const short8*)&bufA[(16 * t + l15) * 72 + 32 + quad * 8];
#pragma unroll
            for (int nt = 0; nt < 4; ++nt) {
                f32x4 u = MFMA16(w[nt * 2], a0, zero);
                c[t][nt] = MFMA16(w[nt * 2 + 1], a1, u);
            }
        }
        __builtin_amdgcn_s_setprio(0);
        f32x4 hb2q[4];
#pragma unroll
        for (int nt = 0; nt < 4; ++nt) hb2q[nt] = *(const f32x4*)&hb2[nt * 16 + quad * 4];
#pragma unroll
        for (int t = 0; t < 3; ++t)
#pragma unroll
            for (int nt = 0; nt < 4; ++nt)
                *(uint2*)&bufB[(16 * t + l15) * 72 + nt * 16 + quad * 4] =
                    pack4_relu(c[t][nt], hb2q[nt]);
    }
    LDS_FENCE();

    // ---- L5: H3^T(A) x V(B) -> D[chan=quad*4+r][point=l15] ----
    f32x4 c5[3];
    {
        const short8 w0 = FRAG(18), w1f = FRAG(19);
        __builtin_amdgcn_s_setprio(1);
#pragma unroll
        for (int t = 0; t < 3; ++t) {
            const short8 a0 = *(const short8*)&bufB[(16 * t + l15) * 72 + quad * 8];
            const short8 a1 = *(const short8*)&bufB[(16 * t + l15) * 72 + 32 + quad * 8];
            c5[t] = MFMA16(w0, a0, zero);
            c5[t] = MFMA16(w1f, a1, c5[t]);
        }
        __builtin_amdgcn_s_setprio(0);
    }
#undef FRAG

    // ---- softmax over 48 densities (wave shuffles; no LDS) ----
    const float d = (lane < NS) ? densities[p0 + lane] : -INFINITY;
    float m = d;
#pragma unroll
    for (int off = 32; off > 0; off >>= 1) m = fmaxf(m, __shfl_xor(m, off));
    const float e = expf(d - m);              // -inf -> 0 for lanes >= 48
    float sum = e;
#pragma unroll
    for (int off = 32; off > 0; off >>= 1) sum += __shfl_xor(sum, off);
    const float wgt = e / sum;
    float wt[3];
#pragma unroll
    for (int t = 0; t < 3; ++t) wt[t] = __shfl(wgt, 16 * t + l15);

    // ---- weighted sum: lane owns points {l15, 16+l15, 32+l15}; channels in
    // regs r=0..2. Reduce over the 16 lanes of each quad group. ----
    const float h30 = hb3[0], h31 = hb3[1], h32 = hb3[2];
    float a0 = 0.0f, a1 = 0.0f, a2 = 0.0f;
#pragma unroll
    for (int t = 0; t < 3; ++t) {
        a0 += wt[t] * sigmoidf(c5[t][0] + h30);
        a1 += wt[t] * sigmoidf(c5[t][1] + h31);
        a2 += wt[t] * sigmoidf(c5[t][2] + h32);
    }
#pragma unroll
    for (int off = 1; off < 16; off <<= 1) {
        a0 += __shfl_xor(a0, off);
        a1 += __shfl_xor(a1, off);
        a2 += __shfl_xor(a2, off);
    }
    if (lane == 0) {
        out[bidb * 3 + 0] = a0;
        out[bidb * 3 + 1] = a1;
        out[bidb * 3 + 2] = a2;
    }
}

extern "C" void kernel_launch(void* const* d_in, const int* in_sizes, int n_in,
                              void* d_out, int out_size, void* d_ws, size_t ws_size,
                              hipStream_t stream) {
    const float* positions = (const float*)d_in[0];
    const float* densities = (const float*)d_in[1];
    const float* normals   = (const float*)d_in[2];
    const float* c2w       = (const float*)d_in[3];
    const float* table     = (const float*)d_in[4];
    const float* w1  = (const float*)d_in[5];
    const float* b1  = (const float*)d_in[6];
    const float* w2  = (const float*)d_in[7];
    const float* b2  = (const float*)d_in[8];
    const float* h1  = (const float*)d_in[9];
    const float* hb1 = (const float*)d_in[10];
    const float* h2  = (const float*)d_in[11];
    const float* hb2 = (const float*)d_in[12];
    const float* h3  = (const float*)d_in[13];
    const float* hb3 = (const float*)d_in[14];
    float* out = (float*)d_out;

    // ws layout: bank (20 KB) only — enc_ws eliminated by fusion
    ushort* bank = (ushort*)d_ws;

    Scales sc;
    const double growth = exp((log(2048.0) - log(16.0)) / 15.0);
    for (int i = 0; i < NLEV; ++i)
        sc.s[i] = (float)floor(16.0 * pow(growth, (double)i));

    bank_kernel<<<1, 256, 0, stream>>>(w1, w2, h1, h2, h3, bank);
    fused_kernel<<<NB, 64, 0, stream>>>(
        positions, densities, normals, c2w, table, bank,
        b1, b2, hb1, hb2, hb3, out, sc);
}

// Round 6
// 199.839 us; speedup vs baseline: 1.4375x; 1.4375x over previous
//
#include <hip/hip_runtime.h>
#include <math.h>
#include <stdint.h>

#define NLEV 16
#define TSIZE (1u << 19)
#define NB 4096
#define NS 48
#define NPTS (NB * NS)
#define CHUNKS (NPTS / 256)          // 768 point-chunks of 256

typedef __attribute__((ext_vector_type(8))) short short8;
typedef __attribute__((ext_vector_type(4))) float f32x4;

struct Scales { float s[NLEV]; };

__device__ __forceinline__ uint32_t hash3(uint32_t x, uint32_t y, uint32_t z) {
    return (x ^ (y * 2654435761u) ^ (z * 805459861u)) & (TSIZE - 1u);
}

__device__ __forceinline__ float sigmoidf(float v) {
    return 1.0f / (1.0f + expf(-v));
}

// fp32 -> bf16 (round to nearest even), raw ushort bits
__device__ __forceinline__ ushort f2b(float f) {
    union { float f; uint32_t u; } v; v.f = f;
    uint32_t r = (v.u + 0x7FFFu + ((v.u >> 16) & 1u)) >> 16;
    return (ushort)r;
}

// relu + pack 2 fp32 -> 1 u32 of 2 bf16 (lo = first arg). Bit-math RNE.
__device__ __forceinline__ uint32_t pk_relu2(float a, float b) {
    a = fmaxf(a, 0.0f);
    b = fmaxf(b, 0.0f);
    return ((uint32_t)f2b(b) << 16) | (uint32_t)f2b(a);
}

#define MFMA16(a, b, c) __builtin_amdgcn_mfma_f32_16x16x32_bf16((a), (b), (c), 0, 0, 0)

// k1: encode — EXACT round-3 kernel (85-91 us, FETCH ~= 70 MB compulsory,
// ~96% of the gather request-rate ceiling). Time-phased level->XCD mapping
// keeps each XCD's table slice <= 4 MB (L2-resident). Round-4 lesson: fusing
// the gather with the MLP destroys this locality (FETCH 498 MB, 3 TB/s
// L2-miss-bound). Last block builds the 20-fragment weight bank:
//   f0..3 W1^T | f4..5 W2^T | f6..9 H1^T | f10..17 H2^T (nt*2+kk) |
//   f18..19 H3^T (cols>=3 zero); frag element [lane][j] = W[k=quad*8+j][out=f*16+l15]
__global__ __launch_bounds__(256) void encode_kernel(
    const float* __restrict__ positions,
    const float* __restrict__ c2w,
    const float* __restrict__ table,
    const float* __restrict__ w1, const float* __restrict__ w2,
    const float* __restrict__ h1, const float* __restrict__ h2,
    const float* __restrict__ h3,
    uint32_t* __restrict__ enc_ws,
    ushort* __restrict__ bank,
    Scales sc)
{
    const int bid = blockIdx.x;
    if (bid == CHUNKS * NLEV) {
        for (int idx = threadIdx.x; idx < 20 * 512; idx += 256) {
            const int f    = idx >> 9;
            const int r    = idx & 511;
            const int lane = r >> 3;
            const int j    = r & 7;
            const int l15  = lane & 15;
            const int quad = lane >> 4;
            const int k8   = quad * 8 + j;
            float val;
            if (f < 4) {
                val = w1[k8 * 64 + f * 16 + l15];
            } else if (f < 6) {
                val = w2[((f - 4) * 32 + k8) * 16 + l15];
            } else if (f < 10) {
                val = h1[k8 * 64 + (f - 6) * 16 + l15];
            } else if (f < 18) {
                const int t = f - 10, nt = t >> 1, kk = t & 1;
                val = h2[(kk * 32 + k8) * 64 + nt * 16 + l15];
            } else {
                val = (l15 < 3) ? h3[((f - 18) * 32 + k8) * 3 + l15] : 0.0f;
            }
            bank[idx] = f2b(val);
        }
        return;
    }

    // phase-based level mapping (XCD = bid % 8 heuristic)
    const int half  = CHUNKS * 8;                  // blocks per phase
    const int ph    = (bid >= half) ? 1 : 0;
    const int q     = bid - ph * half;
    const int x     = q & 7;                       // XCD
    const int l     = x + 8 * ((x & 1) ^ ph);      // wave-uniform level
    const int p     = (q >> 3) * 256 + threadIdx.x;
    const int b     = p / NS;

    const float* M = c2w + b * 12;
    const float px = positions[3 * p + 0];
    const float py = positions[3 * p + 1];
    const float pz = positions[3 * p + 2];
    const float dx = px - M[3], dy = py - M[7], dz = pz - M[11];
    float qx = M[0] * dx + M[4] * dy + M[8] * dz;
    float qy = M[1] * dx + M[5] * dy + M[9] * dz;
    float qz = M[2] * dx + M[6] * dy + M[10] * dz;
    qx = (qx + 1.0f) * 0.5f;
    qy = (qy + 1.0f) * 0.5f;
    qz = (qz + 1.0f) * 0.5f;
    const bool sel = (qx > 0.0f) && (qx < 1.0f) &&
                     (qy > 0.0f) && (qy < 1.0f) &&
                     (qz > 0.0f) && (qz < 1.0f);
    if (!sel) { qx = 0.0f; qy = 0.0f; qz = 0.0f; }

    const float s = sc.s[l];
    const float sx = qx * s, sy = qy * s, sz = qz * s;
    const float fx = floorf(sx), fy = floorf(sy), fz = floorf(sz);
    const float cx = ceilf(sx),  cy = ceilf(sy),  cz = ceilf(sz);
    const float ox = sx - fx, oy = sy - fy, oz = sz - fz;
    const uint32_t fxi = (uint32_t)fx, fyi = (uint32_t)fy, fzi = (uint32_t)fz;
    const uint32_t cxi = (uint32_t)cx, cyi = (uint32_t)cy, czi = (uint32_t)cz;

    const float2* tab = (const float2*)table + (uint32_t)l * TSIZE;
    const float2 g0 = tab[hash3(cxi, cyi, czi)];
    const float2 g1 = tab[hash3(cxi, fyi, czi)];
    const float2 g2 = tab[hash3(fxi, fyi, czi)];
    const float2 g3 = tab[hash3(fxi, cyi, czi)];
    const float2 g4 = tab[hash3(cxi, cyi, fzi)];
    const float2 g5 = tab[hash3(cxi, fyi, fzi)];
    const float2 g6 = tab[hash3(fxi, fyi, fzi)];
    const float2 g7 = tab[hash3(fxi, cyi, fzi)];

    const float omx = 1.0f - ox, omy = 1.0f - oy, omz = 1.0f - oz;
    float f03x = g0.x * ox + g3.x * omx, f03y = g0.y * ox + g3.y * omx;
    float f12x = g1.x * ox + g2.x * omx, f12y = g1.y * ox + g2.y * omx;
    float f56x = g5.x * ox + g6.x * omx, f56y = g5.y * ox + g6.y * omx;
    float f47x = g4.x * ox + g7.x * omx, f47y = g4.y * ox + g7.y * omx;
    float ax = f03x * oy + f12x * omy, ay = f03y * oy + f12y * omy;
    float bx = f47x * oy + f56x * omy, by = f47y * oy + f56y * omy;
    const float ex = ax * oz + bx * omz;
    const float ey = ay * oz + by * omz;
    enc_ws[l * NPTS + p] = ((uint32_t)f2b(ey) << 16) | (uint32_t)f2b(ex);
}

// k2: tail — LDS-FREE MLP + softmax-reduce. 256-thread blocks = 4 independent
// waves, one batch each (no __syncthreads, no LDS, no fences).
// The D->next-B transform preserves the point index on l15; only the feature
// index moves from (quad,reg) to (quad,elem): a pure intra-wave quad
// permutation via __shfl on packed bf16 pairs. Feature algebra:
//   f = nt*16 + quad_src*4 + 2w  ==  khalf*32 + quad_dst*8 + 2jj
//   => nt = khalf*2 + (quad_dst>>1), quad_src = 2*(quad_dst&1) + (jj>>1),
//      w = jj&1.
// All local arrays statically indexed (rule #20); shw selected by constant
// indices + cndmask (fixes round-5 OOB/scratch hazard at L3).
__global__ __launch_bounds__(256) void tail_kernel(
    const uint32_t* __restrict__ enc_ws,
    const float* __restrict__ densities,
    const float* __restrict__ normals,
    const float* __restrict__ c2w,
    const ushort* __restrict__ bank,
    const float* __restrict__ b1, const float* __restrict__ b2,
    const float* __restrict__ hb1, const float* __restrict__ hb2,
    const float* __restrict__ hb3,
    float* __restrict__ out)
{
    const int bidb = blockIdx.x * 4 + (threadIdx.x >> 6);   // batch (1 per wave)
    const int p0   = bidb * NS;
    const int lane = threadIdx.x & 63;
    const int l15  = lane & 15;
    const int quad = lane >> 4;
    const int hiq  = quad >> 1;

    union XU { uint32_t u[4]; short8 s; };

    // ---- X fragments straight from level-major enc_ws (12 coalesced loads).
    // word jj of tile t = enc(pt=16t+l15, lev=quad*4+jj). ----
    XU xu[3];
#pragma unroll
    for (int t = 0; t < 3; ++t)
#pragma unroll
        for (int jj = 0; jj < 4; ++jj)
            xu[t].u[jj] = enc_ws[(quad * 4 + jj) * NPTS + p0 + 16 * t + l15];

    // ---- softmax over 48 densities (early: hides xu load latency) ----
    const float d = (lane < NS) ? densities[p0 + lane] : -INFINITY;
    float m = d;
#pragma unroll
    for (int off = 32; off > 0; off >>= 1) m = fmaxf(m, __shfl_xor(m, off));
    const float e = expf(d - m);              // -inf -> 0 for lanes >= 48
    float sum = e;
#pragma unroll
    for (int off = 32; off > 0; off >>= 1) sum += __shfl_xor(sum, off);
    const float wgt = e / sum;
    float wt[3];
#pragma unroll
    for (int t = 0; t < 3; ++t) wt[t] = __shfl(wgt, 16 * t + l15);

    // ---- SH16: lane computes sh[l15]; 8 batch-uniform packed B words ----
    const float* M = c2w + bidb * 12;
    float shv;
    {
        const float n0 = normals[3 * bidb + 0];
        const float n1 = normals[3 * bidb + 1];
        const float n2 = normals[3 * bidb + 2];
        float x = M[0] * n0 + M[4] * n1 + M[8] * n2;
        float y = M[1] * n0 + M[5] * n1 + M[9] * n2;
        float z = M[2] * n0 + M[6] * n1 + M[10] * n2;
        x = (x + 1.0f) * 0.5f;
        y = (y + 1.0f) * 0.5f;
        z = (z + 1.0f) * 0.5f;
        const float xx = x * x, yy = y * y, zz = z * z;
        float v = 0.28209479177387814f;
        v = (l15 == 1)  ? -0.48860251190291987f * y : v;
        v = (l15 == 2)  ?  0.48860251190291987f * z : v;
        v = (l15 == 3)  ? -0.48860251190291987f * x : v;
        v = (l15 == 4)  ?  1.0925484305920792f * x * y : v;
        v = (l15 == 5)  ? -1.0925484305920792f * y * z : v;
        v = (l15 == 6)  ?  0.94617469575756f * zz - 0.31539156525252f : v;
        v = (l15 == 7)  ? -1.0925484305920792f * x * z : v;
        v = (l15 == 8)  ?  0.5462742152960396f * (xx - yy) : v;
        v = (l15 == 9)  ?  0.5900435899266435f * y * (3.0f * xx - yy) : v;
        v = (l15 == 10) ?  2.890611442640554f * x * y * z : v;
        v = (l15 == 11) ?  0.4570457994644657f * y * (5.0f * zz - 1.0f) : v;
        v = (l15 == 12) ?  0.37317633259011546f * z * (5.0f * zz - 3.0f) : v;
        v = (l15 == 13) ?  0.4570457994644657f * x * (5.0f * zz - 1.0f) : v;
        v = (l15 == 14) ?  1.445305721320277f * z * (xx - yy) : v;
        v = (l15 == 15) ?  0.5900435899266435f * x * (xx - 3.0f * yy) : v;
        shv = v;
    }
    uint32_t shw[8];
#pragma unroll
    for (int i = 0; i < 8; ++i) {
        const float s0 = __shfl(shv, 2 * i);
        const float s1 = __shfl(shv, 2 * i + 1);
        shw[i] = ((uint32_t)f2b(s1) << 16) | (uint32_t)f2b(s0);
    }

    const ushort* fb = bank + lane * 8;
#define FRAG(f) (*(const short8*)(fb + (f) * 512))

    const f32x4 zero = {0.0f, 0.0f, 0.0f, 0.0f};
    const int srcq = 2 * (quad & 1);        // base src quad for this dest quad

    // pw: packed relu'd outputs of the previous 64-wide layer, static-indexed.
    uint32_t pw[3][4][2];

    // ---- L1: W1^T(A) x X(B regs) -> 64, +b1, relu -> pw ----
    {
        short8 w[4];
#pragma unroll
        for (int nt = 0; nt < 4; ++nt) w[nt] = FRAG(nt);
        f32x4 b1q[4];
#pragma unroll
        for (int nt = 0; nt < 4; ++nt) b1q[nt] = *(const f32x4*)&b1[nt * 16 + quad * 4];
        __builtin_amdgcn_s_setprio(1);
#pragma unroll
        for (int t = 0; t < 3; ++t) {
#pragma unroll
            for (int nt = 0; nt < 4; ++nt) {
                const f32x4 c = MFMA16(w[nt], xu[t].s, zero);
                pw[t][nt][0] = pk_relu2(c[0] + b1q[nt][0], c[1] + b1q[nt][1]);
                pw[t][nt][1] = pk_relu2(c[2] + b1q[nt][2], c[3] + b1q[nt][3]);
            }
        }
        __builtin_amdgcn_s_setprio(0);
    }

    // ---- L2: W2^T(A) x A1(B via shuffles) -> 16 geo, +b2, relu -> pg ----
    uint32_t pg[3][2];
    {
        const short8 w0 = FRAG(4), w1f = FRAG(5);
        const f32x4 b2q = *(const f32x4*)&b2[quad * 4];
#pragma unroll
        for (int t = 0; t < 3; ++t) {
            XU a0u, a1u;
#pragma unroll
            for (int jj = 0; jj < 4; ++jj) {
                const int src = 16 * (srcq + (jj >> 1)) + l15;
                const uint32_t v0 = __shfl(pw[t][0][jj & 1], src);
                const uint32_t v1 = __shfl(pw[t][1][jj & 1], src);
                const uint32_t v2 = __shfl(pw[t][2][jj & 1], src);
                const uint32_t v3 = __shfl(pw[t][3][jj & 1], src);
                a0u.u[jj] = hiq ? v1 : v0;
                a1u.u[jj] = hiq ? v3 : v2;
            }
            f32x4 c = MFMA16(w0, a0u.s, zero);
            c = MFMA16(w1f, a1u.s, c);
            pg[t][0] = pk_relu2(c[0] + b2q[0], c[1] + b2q[1]);
            pg[t][1] = pk_relu2(c[2] + b2q[2], c[3] + b2q[3]);
        }
    }

    // ---- L3: H1^T(A) x [SH16|geo](B via shw/shuffles) -> 64, +hb1, relu ----
    {
        short8 w[4];
#pragma unroll
        for (int nt = 0; nt < 4; ++nt) w[nt] = FRAG(6 + nt);
        f32x4 hb1q[4];
#pragma unroll
        for (int nt = 0; nt < 4; ++nt) hb1q[nt] = *(const f32x4*)&hb1[nt * 16 + quad * 4];
#pragma unroll
        for (int t = 0; t < 3; ++t) {
            XU au;
#pragma unroll
            for (int jj = 0; jj < 4; ++jj) {
                const int src = 16 * (srcq + (jj >> 1)) + l15;
                const uint32_t g = __shfl(pg[t][jj & 1], src);
                // constant-index shw, select by quad bits (no runtime array idx)
                const uint32_t s_lo = shw[jj];       // quad 0 rows: SH feats 8qd+2jj
                const uint32_t s_hi = shw[4 + jj];   // quad 1 rows
                const uint32_t sh_sel = (quad & 1) ? s_hi : s_lo;
                au.u[jj] = (quad >= 2) ? g : sh_sel;
            }
            __builtin_amdgcn_s_setprio(1);
#pragma unroll
            for (int nt = 0; nt < 4; ++nt) {
                const f32x4 c = MFMA16(w[nt], au.s, zero);
                pw[t][nt][0] = pk_relu2(c[0] + hb1q[nt][0], c[1] + hb1q[nt][1]);
                pw[t][nt][1] = pk_relu2(c[2] + hb1q[nt][2], c[3] + hb1q[nt][3]);
            }
            __builtin_amdgcn_s_setprio(0);
        }
    }

    // ---- L4: H2^T(A) x U(B via shuffles) -> 64, +hb2, relu -> pw ----
    {
        short8 w[8];
#pragma unroll
        for (int f = 0; f < 8; ++f) w[f] = FRAG(10 + f);
        f32x4 hb2q[4];
#pragma unroll
        for (int nt = 0; nt < 4; ++nt) hb2q[nt] = *(const f32x4*)&hb2[nt * 16 + quad * 4];
#pragma unroll
        for (int t = 0; t < 3; ++t) {
            XU a0u, a1u;
#pragma unroll
            for (int jj = 0; jj < 4; ++jj) {
                const int src = 16 * (srcq + (jj >> 1)) + l15;
                const uint32_t v0 = __shfl(pw[t][0][jj & 1], src);
                const uint32_t v1 = __shfl(pw[t][1][jj & 1], src);
                const uint32_t v2 = __shfl(pw[t][2][jj & 1], src);
                const uint32_t v3 = __shfl(pw[t][3][jj & 1], src);
                a0u.u[jj] = hiq ? v1 : v0;
                a1u.u[jj] = hiq ? v3 : v2;
            }
            __builtin_amdgcn_s_setprio(1);
#pragma unroll
            for (int nt = 0; nt < 4; ++nt) {
                f32x4 u = MFMA16(w[nt * 2], a0u.s, zero);
                const f32x4 c = MFMA16(w[nt * 2 + 1], a1u.s, u);
                pw[t][nt][0] = pk_relu2(c[0] + hb2q[nt][0], c[1] + hb2q[nt][1]);
                pw[t][nt][1] = pk_relu2(c[2] + hb2q[nt][2], c[3] + hb2q[nt][3]);
            }
            __builtin_amdgcn_s_setprio(0);
        }
    }

    // ---- L5: H3^T(A) x V(B via shuffles) -> D[chan=quad*4+r][pt=l15] ----
    f32x4 c5[3];
    {
        const short8 w0 = FRAG(18), w1f = FRAG(19);
#pragma unroll
        for (int t = 0; t < 3; ++t) {
            XU a0u, a1u;
#pragma unroll
            for (int jj = 0; jj < 4; ++jj) {
                const int src = 16 * (srcq + (jj >> 1)) + l15;
                const uint32_t v0 = __shfl(pw[t][0][jj & 1], src);
                const uint32_t v1 = __shfl(pw[t][1][jj & 1], src);
                const uint32_t v2 = __shfl(pw[t][2][jj & 1], src);
                const uint32_t v3 = __shfl(pw[t][3][jj & 1], src);
                a0u.u[jj] = hiq ? v1 : v0;
                a1u.u[jj] = hiq ? v3 : v2;
            }
            f32x4 c = MFMA16(w0, a0u.s, zero);
            c5[t] = MFMA16(w1f, a1u.s, c);
        }
    }
#undef FRAG

    // ---- weighted sum of sigmoid(rgb): quad 0 holds chans 0..2; reduce
    // over the 16 lanes of each quad group; lane 0 writes. ----
    const float h30 = hb3[0], h31 = hb3[1], h32 = hb3[2];
    float a0 = 0.0f, a1 = 0.0f, a2 = 0.0f;
#pragma unroll
    for (int t = 0; t < 3; ++t) {
        a0 += wt[t] * sigmoidf(c5[t][0] + h30);
        a1 += wt[t] * sigmoidf(c5[t][1] + h31);
        a2 += wt[t] * sigmoidf(c5[t][2] + h32);
    }
#pragma unroll
    for (int off = 1; off < 16; off <<= 1) {
        a0 += __shfl_xor(a0, off);
        a1 += __shfl_xor(a1, off);
        a2 += __shfl_xor(a2, off);
    }
    if (lane == 0) {
        out[bidb * 3 + 0] = a0;
        out[bidb * 3 + 1] = a1;
        out[bidb * 3 + 2] = a2;
    }
}

extern "C" void kernel_launch(void* const* d_in, const int* in_sizes, int n_in,
                              void* d_out, int out_size, void* d_ws, size_t ws_size,
                              hipStream_t stream) {
    const float* positions = (const float*)d_in[0];
    const float* densities = (const float*)d_in[1];
    const float* normals   = (const float*)d_in[2];
    const float* c2w       = (const float*)d_in[3];
    const float* table     = (const float*)d_in[4];
    const float* w1  = (const float*)d_in[5];
    const float* b1  = (const float*)d_in[6];
    const float* w2  = (const float*)d_in[7];
    const float* b2  = (const float*)d_in[8];
    const float* h1  = (const float*)d_in[9];
    const float* hb1 = (const float*)d_in[10];
    const float* h2  = (const float*)d_in[11];
    const float* hb2 = (const float*)d_in[12];
    const float* h3  = (const float*)d_in[13];
    const float* hb3 = (const float*)d_in[14];
    float* out = (float*)d_out;

    // ws layout: bank (20 KB) | enc (NLEV*NPTS u32 = 12.6 MB)
    ushort*   bank   = (ushort*)d_ws;
    uint32_t* enc_ws = (uint32_t*)((char*)d_ws + 20 * 1024);

    Scales sc;
    const double growth = exp((log(2048.0) - log(16.0)) / 15.0);
    for (int i = 0; i < NLEV; ++i)
        sc.s[i] = (float)floor(16.0 * pow(growth, (double)i));

    const int enc_blocks = CHUNKS * NLEV + 1;   // +1 = bank-build block
    encode_kernel<<<enc_blocks, 256, 0, stream>>>(
        positions, c2w, table, w1, w2, h1, h2, h3, enc_ws, bank, sc);
    tail_kernel<<<NB / 4, 256, 0, stream>>>(
        enc_ws, densities, normals, c2w, bank, b1, b2, hb1, hb2, hb3, out);
}